// Round 5
// baseline (182.046 us; speedup 1.0000x reference)
//
#include <hip/hip_runtime.h>
#include <cstdint>
#include <cstddef>

#define HID 1024
#define NH 16
#define HD 64
#define BB 2
#define LL 2048
#define MM (BB*LL)       // 4096 rows
#define CHUNK 64
#define NT (LL/CHUNK)    // 32 chunks
#define BHn (BB*NH)      // 32 (b,h) chains

typedef __bf16 bf16;
typedef __attribute__((ext_vector_type(8))) __bf16 bf16x8;
typedef __attribute__((ext_vector_type(4))) float f32x4;

__device__ __forceinline__ f32x4 mfma16(bf16x8 a, bf16x8 b, f32x4 c){
  return __builtin_amdgcn_mfma_f32_16x16x32_bf16(a, b, c, 0, 0, 0);
}

__device__ __forceinline__ void gload16(const void* g, void* l){
  __builtin_amdgcn_global_load_lds(
      (const __attribute__((address_space(1))) unsigned int*)g,
      (__attribute__((address_space(3))) unsigned int*)l, 16, 0, 0);
}

__device__ __forceinline__ void barx(){
  asm volatile("" ::: "memory");
  __builtin_amdgcn_s_barrier();
  asm volatile("" ::: "memory");
}

#define WAITVM(N) asm volatile("s_waitcnt vmcnt(" #N ")" ::: "memory")

// ---------------- fused cast fp32 -> bf16 (x + 4 weights, one launch) ----------------
__global__ __launch_bounds__(256) void cast_all_k(
    const float* __restrict__ x,  const float* __restrict__ w0,
    const float* __restrict__ w1, const float* __restrict__ w2, const float* __restrict__ w3,
    bf16* __restrict__ xb, bf16* __restrict__ d0, bf16* __restrict__ d1,
    bf16* __restrict__ d2, bf16* __restrict__ d3)
{
  int bid = blockIdx.x;                   // 0..8191
  const float* s; bf16* d; int base;
  if (bid < 4096){ s = x; d = xb; base = bid; }
  else {
    int w = (bid - 4096) >> 10, r = (bid - 4096) & 1023;
    s = (w==0)?w0:(w==1)?w1:(w==2)?w2:w3;
    d = (w==0)?d0:(w==1)?d1:(w==2)?d2:d3;
    base = r;
  }
  int i = base*256 + threadIdx.x;
  float4 v = ((const float4*)s)[i];
  union { bf16 h[4]; uint2 u; } pk;
  pk.h[0]=(bf16)v.x; pk.h[1]=(bf16)v.y; pk.h[2]=(bf16)v.z; pk.h[3]=(bf16)v.w;
  *((uint2*)(d + 4*(size_t)i)) = pk.u;
}

// ---------------- software-pipelined 8-wave GEMM ----------------
// (unchanged from round 4; see comments there)
template<int MODE>
__global__ __launch_bounds__(512, 2) void gemm8_k(
    const bf16* __restrict__ A,
    const bf16* __restrict__ W0, const bf16* __restrict__ W1, const bf16* __restrict__ W2,
    bf16* __restrict__ Qo, bf16* __restrict__ Kn, bf16* __restrict__ Vn,
    float* __restrict__ Outf)
{
  constexpr int BM  = (MODE==0) ? 256 : 128;
  constexpr int BN  = (MODE==0) ? 256 : 128;
  constexpr int AP  = BM/128;
  constexpr int BP  = BN/128;
  constexpr int PPT = AP + BP;
  constexpr int NA  = BM/32;
  constexpr int NBF = BN/64;
  constexpr int NKT = HID/32;
  __shared__ bf16 lds[4][PPT][128*32];

  const int tid = threadIdx.x;
  const int wv = tid >> 6, lane = tid & 63;
  const int lrow = lane & 15, g4 = lane >> 4;
  const int wr = wv >> 2, wc = wv & 3;
  int bn = blockIdx.x, wsel = 0;
  const bf16* W = W0;
  if (MODE==0){ wsel = bn >> 2; bn &= 3; W = (wsel==0)?W0:((wsel==1)?W1:W2); }
  const int row0 = blockIdx.y*BM, col0 = bn*BN;

  const int sr = tid >> 2, sc = tid & 3;
  const int scs = sc ^ ((sr>>1)&3);              // pre-swizzled source chunk
  const bf16* gA0 = A + (size_t)(row0 + sr)*HID + scs*8;
  const bf16* gA1 = gA0 + (size_t)128*HID;
  const bf16* gB0 = W + (size_t)(col0 + sr)*HID + scs*8;
  const bf16* gB1 = gB0 + (size_t)128*HID;
  const int ldst = tid*8;

  auto stage_tile = [&](int u){
    const int buf = u & 3;
    gload16(gA0 + u*32, (void*)&lds[buf][0][ldst]);
    if constexpr (AP==2) gload16(gA1 + u*32, (void*)&lds[buf][1][ldst]);
    gload16(gB0 + u*32, (void*)&lds[buf][AP][ldst]);
    if constexpr (BP==2) gload16(gB1 + u*32, (void*)&lds[buf][AP+1][ldst]);
  };

  const int koff = (g4 ^ ((lrow>>1)&3)) << 3;

  auto read_frags = [&](int u, bf16x8 (&fa)[NA], bf16x8 (&fb)[NBF]){
    const int buf = u & 3;
    #pragma unroll
    for (int i=0;i<NA;i++){
      if constexpr (MODE==0)
        fa[i] = *(const bf16x8*)&lds[buf][wr][((i*16+lrow)<<5) + koff];
      else
        fa[i] = *(const bf16x8*)&lds[buf][0][((wr*64 + i*16+lrow)<<5) + koff];
    }
    #pragma unroll
    for (int j=0;j<NBF;j++){
      if constexpr (MODE==0)
        fb[j] = *(const bf16x8*)&lds[buf][2+(wc>>1)][(((wc&1)*64 + j*16+lrow)<<5) + koff];
      else
        fb[j] = *(const bf16x8*)&lds[buf][1][((wc*32 + j*16+lrow)<<5) + koff];
    }
  };

  f32x4 acc[NA][NBF] = {};
  auto do_mfma = [&](bf16x8 (&fa)[NA], bf16x8 (&fb)[NBF]){
    __builtin_amdgcn_s_setprio(1);
    #pragma unroll
    for (int i=0;i<NA;i++)
      #pragma unroll
      for (int j=0;j<NBF;j++)
        acc[i][j] = mfma16(fa[i], fb[j], acc[i][j]);
    __builtin_amdgcn_s_setprio(0);
  };

  stage_tile(0); stage_tile(1); stage_tile(2);
  if constexpr (MODE==0) WAITVM(8); else WAITVM(4);
  barx();
  bf16x8 fEa[NA], fEb[NBF], fOa[NA], fOb[NBF];
  read_frags(0, fEa, fEb);

  for (int t=0; t<NKT; t+=2){
    if (t+3 < NKT)      { stage_tile(t+3); if constexpr (MODE==0) WAITVM(8); else WAITVM(4); }
    else if (t+3 == NKT){ if constexpr (MODE==0) WAITVM(4); else WAITVM(2); }
    else                { WAITVM(0); }
    barx();
    read_frags(t+1, fOa, fOb);
    do_mfma(fEa, fEb);
    const int t2 = t+1;
    if (t2 < NKT-1){
      if (t2+3 < NKT)      { stage_tile(t2+3); if constexpr (MODE==0) WAITVM(8); else WAITVM(4); }
      else if (t2+3 == NKT){ if constexpr (MODE==0) WAITVM(4); else WAITVM(2); }
      else                 { WAITVM(0); }
      barx();
      read_frags(t2+1, fEa, fEb);
    }
    do_mfma(fOa, fOb);
  }

  #pragma unroll
  for (int i=0;i<NA;i++){
    const int m0 = row0 + wr*(BM/2) + i*16 + g4*4;
    #pragma unroll
    for (int j=0;j<NBF;j++){
      const int c = col0 + wc*(BN/4) + j*16 + lrow;
      #pragma unroll
      for (int r=0;r<4;r++){
        float v = acc[i][j][r];
        if (MODE==1){
          Outf[(size_t)(m0+r)*HID + c] = v;
        } else {
          if (wsel<2) v = v>0.f ? v+1.f : __expf(v);   // elu(v)+1
          bf16 bv = (bf16)v;
          if      (wsel==0) Qo[(size_t)(m0+r)*HID + c] = bv;
          else if (wsel==1) Kn[(size_t)(m0+r)*HID + c] = bv;
          else              Vn[(size_t)(m0+r)*HID + c] = bv;
        }
      }
    }
  }
}

// ---------------- scan_k: fused per-chunk K^T/V^T outer products + exclusive scan ----------------
// grid = BHn blocks (one per (b,h)), 256 thr (4 waves, each owns a 32x32 slab of S).
// Per chunk t: LDS-transpose K,V chunk (double-buffered, reg-staged), store running
// S (fp32 regs) as bf16 Sexcl[t] BEFORE update, then S += V^T K via 8 MFMAs.
// Wave 0 also maintains ksum exclusive scan -> ksx.
#define SPAD 78
__global__ __launch_bounds__(256) void scan_k(const bf16* __restrict__ Kn, const bf16* __restrict__ Vn,
                                              bf16* __restrict__ Sexcl, float* __restrict__ ksx)
{
  __shared__ bf16 KT[2][64*SPAD];
  __shared__ bf16 VT[2][64*SPAD];
  const int bh = blockIdx.x;
  const int b = bh>>4, h = bh&15;
  const int tid = threadIdx.x;
  const int wv = tid>>6, lane = tid&63;
  const int lrow = lane&15, g4 = lane>>4, lk8 = g4*8;
  const int we = wv>>1, wd = wv&1;
  const int sj = tid>>2, c4 = tid&3;       // staging: 4 lanes per row, 16-col groups
  const bf16* kbase = Kn + ((size_t)b*LL)*HID + h*HD;
  const bf16* vbase = Vn + ((size_t)b*LL)*HID + h*HD;

  bf16x8 kr0, kr1, vr0, vr1;
  auto gload = [&](int t){
    const bf16* ks = kbase + (size_t)(t*CHUNK + sj)*HID + c4*16;
    const bf16* vs = vbase + (size_t)(t*CHUNK + sj)*HID + c4*16;
    kr0 = *(const bf16x8*)&ks[0]; kr1 = *(const bf16x8*)&ks[8];
    vr0 = *(const bf16x8*)&vs[0]; vr1 = *(const bf16x8*)&vs[8];
  };
  auto lwrite = [&](int buf){
    #pragma unroll
    for (int e=0;e<8;e++){
      KT[buf][(c4*16+e)*SPAD + sj]   = kr0[e];
      KT[buf][(c4*16+8+e)*SPAD + sj] = kr1[e];
      VT[buf][(c4*16+e)*SPAD + sj]   = vr0[e];
      VT[buf][(c4*16+8+e)*SPAD + sj] = vr1[e];
    }
  };

  f32x4 S[2][2] = {};
  float kv = 0.f;
  gload(0); lwrite(0);
  __syncthreads();

  for (int t=0; t<NT; ++t){
    const int buf = t & 1;
    if (t+1 < NT) gload(t+1);
    // exclusive store of current state
    bf16* so = Sexcl + ((size_t)bh*NT + t)*4096;
    #pragma unroll
    for (int i=0;i<2;i++)
      #pragma unroll
      for (int j2=0;j2<2;j2++)
        #pragma unroll
        for (int r=0;r<4;r++)
          so[(we*32 + i*16 + g4*4 + r)*64 + wd*32 + j2*16 + lrow] = (bf16)S[i][j2][r];
    if (wv==0){
      ksx[((size_t)bh*NT + t)*64 + lane] = kv;
      float s = 0.f;
      #pragma unroll
      for (int c8=0;c8<8;c8++){
        bf16x8 k8 = *(const bf16x8*)&KT[buf][lane*SPAD + c8*8];
        #pragma unroll
        for (int u=0;u<8;u++) s += (float)k8[u];
      }
      kv += s;
    }
    // S += V^T K  (A rows = e from VT, B rows = d from KT, k = j)
    bf16x8 fa[2], fb[2];
    #pragma unroll
    for (int kk=0;kk<2;kk++){
      #pragma unroll
      for (int i=0;i<2;i++)
        fa[i] = *(const bf16x8*)&VT[buf][(we*32 + i*16 + lrow)*SPAD + kk*32 + lk8];
      #pragma unroll
      for (int j2=0;j2<2;j2++)
        fb[j2] = *(const bf16x8*)&KT[buf][(wd*32 + j2*16 + lrow)*SPAD + kk*32 + lk8];
      #pragma unroll
      for (int i=0;i<2;i++)
        #pragma unroll
        for (int j2=0;j2<2;j2++)
          S[i][j2] = mfma16(fa[i], fb[j2], S[i][j2]);
    }
    if (t+1 < NT) lwrite((t+1)&1);
    __syncthreads();
  }
}

// ---------------- pass3: per (b,h,chunk) output ----------------
// O = (mask(Q Kc^T) Vc + Q Sprev) / max(q.ksum_prev + rowsum(mask(Q Kc^T)), 1e-6)
// V chunk read row-major from Vn, transposed through LDS (pad 78).
__global__ __launch_bounds__(64) void pass3_k(const bf16* __restrict__ Q, const bf16* __restrict__ Kn,
                                              const bf16* __restrict__ Sexcl, const bf16* __restrict__ Vn,
                                              const float* __restrict__ ksx, bf16* __restrict__ Obuf)
{
  __shared__ bf16 P[64*72];
  __shared__ bf16 VT[64*SPAD];
  const int blk = blockIdx.x;
  const int bh = blk>>5, t = blk&(NT-1);
  const int b = bh>>4, h = bh&15;
  const int lane = threadIdx.x;
  const int lrow = lane&15, g4 = lane>>4, lk8 = g4*8;
  const int sj4 = lane>>2, c4 = lane&3;    // V staging: 4 lanes/row, 16-col groups
  const bf16* qb = Q  + ((size_t)(b*LL + t*CHUNK))*HID + h*HD;
  const bf16* kb = Kn + ((size_t)(b*LL + t*CHUNK))*HID + h*HD;
  const bf16* vb = Vn + ((size_t)(b*LL + t*CHUNK))*HID + h*HD;

  // issue V loads early (4 row-passes x 32 cols per lane)
  bf16x8 vv[8];
  #pragma unroll
  for (int p=0;p<4;p++){
    const bf16* vr = vb + (size_t)(p*16 + sj4)*HID + c4*16;
    vv[p*2+0] = *(const bf16x8*)&vr[0];
    vv[p*2+1] = *(const bf16x8*)&vr[8];
  }

  bf16x8 aq[4][2], bk[4][2];
  #pragma unroll
  for (int i=0;i<4;i++)
    #pragma unroll
    for (int kk=0;kk<2;kk++){
      aq[i][kk] = *(const bf16x8*)&qb[(size_t)(i*16+lrow)*HID + kk*32 + lk8];
      bk[i][kk] = *(const bf16x8*)&kb[(size_t)(i*16+lrow)*HID + kk*32 + lk8];
    }
  f32x4 sacc[4][4] = {};
  #pragma unroll
  for (int i=0;i<4;i++)
    #pragma unroll
    for (int j=0;j<4;j++)
      #pragma unroll
      for (int kk=0;kk<2;kk++)
        sacc[i][j] = mfma16(aq[i][kk], bk[j][kk], sacc[i][j]);
  float rs[4][4];
  #pragma unroll
  for (int i=0;i<4;i++)
    #pragma unroll
    for (int r=0;r<4;r++){
      int irow = i*16 + g4*4 + r;
      float p = 0.f;
      #pragma unroll
      for (int j=0;j<4;j++){
        int jcol = j*16 + lrow;
        float v = (jcol <= irow) ? sacc[i][j][r] : 0.f;
        sacc[i][j][r] = v;
        p += v;
      }
      p += __shfl_xor(p,1); p += __shfl_xor(p,2);
      p += __shfl_xor(p,4); p += __shfl_xor(p,8);
      rs[i][r] = p;
    }
  #pragma unroll
  for (int i=0;i<4;i++)
    #pragma unroll
    for (int j=0;j<4;j++)
      #pragma unroll
      for (int r=0;r<4;r++)
        P[(i*16+g4*4+r)*72 + j*16+lrow] = (bf16)sacc[i][j][r];
  // V -> VT_lds transpose (VT[e][j])
  #pragma unroll
  for (int p=0;p<4;p++)
    #pragma unroll
    for (int u=0;u<8;u++){
      VT[(c4*16+u)*SPAD   + p*16 + sj4] = vv[p*2+0][u];
      VT[(c4*16+8+u)*SPAD + p*16 + sj4] = vv[p*2+1][u];
    }
  // normalizer inter part
  const float* kp = ksx + (size_t)blk*64;
  float zA[4];
  #pragma unroll
  for (int i=0;i<4;i++){
    float s = 0.f;
    #pragma unroll
    for (int kk=0;kk<2;kk++){
      const float* k8 = kp + kk*32 + lk8;
      bf16x8 q = aq[i][kk];
      #pragma unroll
      for (int j=0;j<8;j++) s += (float)q[j] * k8[j];
    }
    s += __shfl_xor(s,16); s += __shfl_xor(s,32);
    zA[i] = s;
  }
  // inter: O += Q @ Sprev
  const bf16* sb = Sexcl + (size_t)blk*4096;
  f32x4 oacc[4][4] = {};
  bf16x8 bs[4][2];
  #pragma unroll
  for (int j=0;j<4;j++)
    #pragma unroll
    for (int kk=0;kk<2;kk++)
      bs[j][kk] = *(const bf16x8*)&sb[(size_t)(j*16+lrow)*64 + kk*32 + lk8];
  #pragma unroll
  for (int i=0;i<4;i++)
    #pragma unroll
    for (int j=0;j<4;j++)
      #pragma unroll
      for (int kk=0;kk<2;kk++)
        oacc[i][j] = mfma16(aq[i][kk], bs[j][kk], oacc[i][j]);
  __syncthreads();                         // P + VT visible
  // intra: O += P @ Vc
  bf16x8 bv[4][2], ap[4][2];
  #pragma unroll
  for (int j=0;j<4;j++)
    #pragma unroll
    for (int kk=0;kk<2;kk++)
      bv[j][kk] = *(const bf16x8*)&VT[(j*16+lrow)*SPAD + kk*32 + lk8];
  #pragma unroll
  for (int i=0;i<4;i++)
    #pragma unroll
    for (int kk=0;kk<2;kk++)
      ap[i][kk] = *(const bf16x8*)&P[(i*16+lrow)*72 + kk*32 + lk8];
  #pragma unroll
  for (int i=0;i<4;i++)
    #pragma unroll
    for (int j=0;j<4;j++)
      #pragma unroll
      for (int kk=0;kk<2;kk++)
        oacc[i][j] = mfma16(ap[i][kk], bv[j][kk], oacc[i][j]);
  // normalize + store
  bf16* ob = Obuf + ((size_t)(b*LL + t*CHUNK))*HID + h*HD;
  #pragma unroll
  for (int i=0;i<4;i++)
    #pragma unroll
    for (int r=0;r<4;r++){
      float z = __shfl(zA[i], g4*4 + r) + rs[i][r];
      z = fmaxf(z, 1e-6f);
      float inv = 1.0f/z;
      int irow = i*16 + g4*4 + r;
      #pragma unroll
      for (int j=0;j<4;j++)
        ob[(size_t)irow*HID + j*16+lrow] = (bf16)(oacc[i][j][r]*inv);
    }
}

// ---------------- launch ----------------
extern "C" void kernel_launch(void* const* d_in, const int* in_sizes, int n_in,
                              void* d_out, int out_size, void* d_ws, size_t ws_size,
                              hipStream_t stream)
{
  const float* x  = (const float*)d_in[0];
  const float* Wq = (const float*)d_in[1];
  const float* Wk = (const float*)d_in[2];
  const float* Wv = (const float*)d_in[3];
  const float* Wo = (const float*)d_in[4];
  float* out = (float*)d_out;

  char* p = (char*)d_ws;
  auto alloc = [&](size_t bytes){ void* r = (void*)p; p += (bytes + 255) & ~(size_t)255; return r; };
  bf16* xb   = (bf16*)alloc((size_t)MM*HID*2);
  bf16* Wqb  = (bf16*)alloc((size_t)HID*HID*2);
  bf16* Wkb  = (bf16*)alloc((size_t)HID*HID*2);
  bf16* Wvb  = (bf16*)alloc((size_t)HID*HID*2);
  bf16* Wob  = (bf16*)alloc((size_t)HID*HID*2);
  bf16* Qb   = (bf16*)alloc((size_t)MM*HID*2);
  bf16* Knb  = (bf16*)alloc((size_t)MM*HID*2);
  bf16* Vnb  = (bf16*)alloc((size_t)MM*HID*2);
  bf16* Ob   = (bf16*)alloc((size_t)MM*HID*2);
  bf16*  Sexcl = (bf16*) alloc((size_t)BHn*NT*4096*2);  // 8 MB
  float* ksx   = (float*)alloc((size_t)BHn*NT*64*4);

  cast_all_k<<<dim3(8192), 256, 0, stream>>>(x, Wq,Wk,Wv,Wo, xb, Wqb,Wkb,Wvb,Wob);
  gemm8_k<0><<<dim3(12,16), 512, 0, stream>>>(xb, Wqb,Wkb,Wvb, Qb,Knb,Vnb, nullptr);
  scan_k<<<dim3(BHn), 256, 0, stream>>>(Knb, Vnb, Sexcl, ksx);
  pass3_k<<<dim3(BHn*NT), 64, 0, stream>>>(Qb, Knb, Sexcl, Vnb, ksx, Ob);
  gemm8_k<1><<<dim3(8,32), 512, 0, stream>>>(Ob, Wob,nullptr,nullptr, nullptr,nullptr,nullptr, out);
}

// Round 6
// 159.058 us; speedup vs baseline: 1.1445x; 1.1445x over previous
//
#include <hip/hip_runtime.h>
#include <cstdint>
#include <cstddef>

#define HID 1024
#define NH 16
#define HD 64
#define BB 2
#define LL 2048
#define MM (BB*LL)       // 4096 rows
#define CHUNK 64
#define NT (LL/CHUNK)    // 32 chunks
#define BHn (BB*NH)      // 32 (b,h) chains
#define SP 72            // LDS pad stride (multiple of 8 for b128 reads)

typedef __bf16 bf16;
typedef __attribute__((ext_vector_type(8))) __bf16 bf16x8;
typedef __attribute__((ext_vector_type(4))) float f32x4;

__device__ __forceinline__ f32x4 mfma16(bf16x8 a, bf16x8 b, f32x4 c){
  return __builtin_amdgcn_mfma_f32_16x16x32_bf16(a, b, c, 0, 0, 0);
}

__device__ __forceinline__ void gload16(const void* g, void* l){
  __builtin_amdgcn_global_load_lds(
      (const __attribute__((address_space(1))) unsigned int*)g,
      (__attribute__((address_space(3))) unsigned int*)l, 16, 0, 0);
}

__device__ __forceinline__ void barx(){
  asm volatile("" ::: "memory");
  __builtin_amdgcn_s_barrier();
  asm volatile("" ::: "memory");
}

#define WAITVM(N) asm volatile("s_waitcnt vmcnt(" #N ")" ::: "memory")

// ---------------- fused cast fp32 -> bf16 (x + 4 weights, one launch) ----------------
__global__ __launch_bounds__(256) void cast_all_k(
    const float* __restrict__ x,  const float* __restrict__ w0,
    const float* __restrict__ w1, const float* __restrict__ w2, const float* __restrict__ w3,
    bf16* __restrict__ xb, bf16* __restrict__ d0, bf16* __restrict__ d1,
    bf16* __restrict__ d2, bf16* __restrict__ d3)
{
  int bid = blockIdx.x;                   // 0..8191
  const float* s; bf16* d; int base;
  if (bid < 4096){ s = x; d = xb; base = bid; }
  else {
    int w = (bid - 4096) >> 10, r = (bid - 4096) & 1023;
    s = (w==0)?w0:(w==1)?w1:(w==2)?w2:w3;
    d = (w==0)?d0:(w==1)?d1:(w==2)?d2:d3;
    base = r;
  }
  int i = base*256 + threadIdx.x;
  float4 v = ((const float4*)s)[i];
  union { bf16 h[4]; uint2 u; } pk;
  pk.h[0]=(bf16)v.x; pk.h[1]=(bf16)v.y; pk.h[2]=(bf16)v.z; pk.h[3]=(bf16)v.w;
  *((uint2*)(d + 4*(size_t)i)) = pk.u;
}

// ---------------- software-pipelined 8-wave GEMM ----------------
// (unchanged from round 4; see comments there)
template<int MODE>
__global__ __launch_bounds__(512, 2) void gemm8_k(
    const bf16* __restrict__ A,
    const bf16* __restrict__ W0, const bf16* __restrict__ W1, const bf16* __restrict__ W2,
    bf16* __restrict__ Qo, bf16* __restrict__ Kn, bf16* __restrict__ Vn,
    float* __restrict__ Outf)
{
  constexpr int BM  = (MODE==0) ? 256 : 128;
  constexpr int BN  = (MODE==0) ? 256 : 128;
  constexpr int AP  = BM/128;
  constexpr int BP  = BN/128;
  constexpr int PPT = AP + BP;
  constexpr int NA  = BM/32;
  constexpr int NBF = BN/64;
  constexpr int NKT = HID/32;
  __shared__ bf16 lds[4][PPT][128*32];

  const int tid = threadIdx.x;
  const int wv = tid >> 6, lane = tid & 63;
  const int lrow = lane & 15, g4 = lane >> 4;
  const int wr = wv >> 2, wc = wv & 3;
  int bn = blockIdx.x, wsel = 0;
  const bf16* W = W0;
  if (MODE==0){ wsel = bn >> 2; bn &= 3; W = (wsel==0)?W0:((wsel==1)?W1:W2); }
  const int row0 = blockIdx.y*BM, col0 = bn*BN;

  const int sr = tid >> 2, sc = tid & 3;
  const int scs = sc ^ ((sr>>1)&3);              // pre-swizzled source chunk
  const bf16* gA0 = A + (size_t)(row0 + sr)*HID + scs*8;
  const bf16* gA1 = gA0 + (size_t)128*HID;
  const bf16* gB0 = W + (size_t)(col0 + sr)*HID + scs*8;
  const bf16* gB1 = gB0 + (size_t)128*HID;
  const int ldst = tid*8;

  auto stage_tile = [&](int u){
    const int buf = u & 3;
    gload16(gA0 + u*32, (void*)&lds[buf][0][ldst]);
    if constexpr (AP==2) gload16(gA1 + u*32, (void*)&lds[buf][1][ldst]);
    gload16(gB0 + u*32, (void*)&lds[buf][AP][ldst]);
    if constexpr (BP==2) gload16(gB1 + u*32, (void*)&lds[buf][AP+1][ldst]);
  };

  const int koff = (g4 ^ ((lrow>>1)&3)) << 3;

  auto read_frags = [&](int u, bf16x8 (&fa)[NA], bf16x8 (&fb)[NBF]){
    const int buf = u & 3;
    #pragma unroll
    for (int i=0;i<NA;i++){
      if constexpr (MODE==0)
        fa[i] = *(const bf16x8*)&lds[buf][wr][((i*16+lrow)<<5) + koff];
      else
        fa[i] = *(const bf16x8*)&lds[buf][0][((wr*64 + i*16+lrow)<<5) + koff];
    }
    #pragma unroll
    for (int j=0;j<NBF;j++){
      if constexpr (MODE==0)
        fb[j] = *(const bf16x8*)&lds[buf][2+(wc>>1)][(((wc&1)*64 + j*16+lrow)<<5) + koff];
      else
        fb[j] = *(const bf16x8*)&lds[buf][1][((wc*32 + j*16+lrow)<<5) + koff];
    }
  };

  f32x4 acc[NA][NBF] = {};
  auto do_mfma = [&](bf16x8 (&fa)[NA], bf16x8 (&fb)[NBF]){
    __builtin_amdgcn_s_setprio(1);
    #pragma unroll
    for (int i=0;i<NA;i++)
      #pragma unroll
      for (int j=0;j<NBF;j++)
        acc[i][j] = mfma16(fa[i], fb[j], acc[i][j]);
    __builtin_amdgcn_s_setprio(0);
  };

  stage_tile(0); stage_tile(1); stage_tile(2);
  if constexpr (MODE==0) WAITVM(8); else WAITVM(4);
  barx();
  bf16x8 fEa[NA], fEb[NBF], fOa[NA], fOb[NBF];
  read_frags(0, fEa, fEb);

  for (int t=0; t<NKT; t+=2){
    if (t+3 < NKT)      { stage_tile(t+3); if constexpr (MODE==0) WAITVM(8); else WAITVM(4); }
    else if (t+3 == NKT){ if constexpr (MODE==0) WAITVM(4); else WAITVM(2); }
    else                { WAITVM(0); }
    barx();
    read_frags(t+1, fOa, fOb);
    do_mfma(fEa, fEb);
    const int t2 = t+1;
    if (t2 < NKT-1){
      if (t2+3 < NKT)      { stage_tile(t2+3); if constexpr (MODE==0) WAITVM(8); else WAITVM(4); }
      else if (t2+3 == NKT){ if constexpr (MODE==0) WAITVM(4); else WAITVM(2); }
      else                 { WAITVM(0); }
      barx();
      read_frags(t2+1, fEa, fEb);
    }
    do_mfma(fOa, fOb);
  }

  #pragma unroll
  for (int i=0;i<NA;i++){
    const int m0 = row0 + wr*(BM/2) + i*16 + g4*4;
    #pragma unroll
    for (int j=0;j<NBF;j++){
      const int c = col0 + wc*(BN/4) + j*16 + lrow;
      #pragma unroll
      for (int r=0;r<4;r++){
        float v = acc[i][j][r];
        if (MODE==1){
          Outf[(size_t)(m0+r)*HID + c] = v;
        } else {
          if (wsel<2) v = v>0.f ? v+1.f : __expf(v);   // elu(v)+1
          bf16 bv = (bf16)v;
          if      (wsel==0) Qo[(size_t)(m0+r)*HID + c] = bv;
          else if (wsel==1) Kn[(size_t)(m0+r)*HID + c] = bv;
          else              Vn[(size_t)(m0+r)*HID + c] = bv;
        }
      }
    }
  }
}

// ---------------- pass1: per-chunk SkvT + ksum, 4-wave blocks, in-LDS transpose --------
// grid = BHn*NT blocks x 256 thr. Reads row-major Kn,Vn (coalesced), transposes the
// 64x64 chunk in LDS once, then wave `we` computes e-strip rows [we*16,we*16+16) of
// S^T[e][d] = sum_j V[j][e] K[j][d] via 8 MFMAs. ksum rows split across waves.
__global__ __launch_bounds__(256) void pass1_k(const bf16* __restrict__ Kn, const bf16* __restrict__ Vn,
                                               float* __restrict__ SkvT, float* __restrict__ ksum)
{
  __shared__ bf16 KT[64*SP];
  __shared__ bf16 VT[64*SP];
  const int blk = blockIdx.x;                 // bh*NT + t
  const int bh = blk >> 5, t = blk & (NT-1);
  const int b = bh>>4, h = bh&15;
  const int tid = threadIdx.x;
  const int we = tid >> 6, lane = tid & 63;
  const int lrow = lane&15, g4 = lane>>4, lk8 = g4*8;
  const int sj = tid >> 2, c4 = tid & 3;      // staging: 4 threads per source row
  const bf16* kb = Kn + ((size_t)(b*LL + t*CHUNK))*HID + h*HD;
  const bf16* vb = Vn + ((size_t)(b*LL + t*CHUNK))*HID + h*HD;

  // load + transpose (one shot, all 256 threads)
  {
    const bf16* ks = kb + (size_t)sj*HID + c4*16;
    const bf16* vs = vb + (size_t)sj*HID + c4*16;
    bf16x8 kr0 = *(const bf16x8*)&ks[0], kr1 = *(const bf16x8*)&ks[8];
    bf16x8 vr0 = *(const bf16x8*)&vs[0], vr1 = *(const bf16x8*)&vs[8];
    #pragma unroll
    for (int e=0;e<8;e++){
      KT[(c4*16+e)*SP + sj]   = kr0[e];
      KT[(c4*16+8+e)*SP + sj] = kr1[e];
      VT[(c4*16+e)*SP + sj]   = vr0[e];
      VT[(c4*16+8+e)*SP + sj] = vr1[e];
    }
  }
  __syncthreads();

  // wave we: S^T rows [we*16, we*16+16)
  f32x4 acc[4] = {};
  #pragma unroll
  for (int kk=0;kk<2;kk++){
    bf16x8 fa = *(const bf16x8*)&VT[(we*16 + lrow)*SP + kk*32 + lk8];
    #pragma unroll
    for (int j=0;j<4;j++){
      bf16x8 fb = *(const bf16x8*)&KT[(j*16 + lrow)*SP + kk*32 + lk8];
      acc[j] = mfma16(fa, fb, acc[j]);
    }
  }
  float* so = SkvT + (size_t)blk*4096;
  #pragma unroll
  for (int j=0;j<4;j++)
    #pragma unroll
    for (int r=0;r<4;r++)
      so[(we*16 + g4*4 + r)*64 + j*16 + lrow] = acc[j][r];

  // ksum: wave we covers K^T rows we*16+lrow; segment g4*16
  {
    const int row = we*16 + lrow;
    float s = 0.f;
    #pragma unroll
    for (int u=0;u<2;u++){
      bf16x8 k8 = *(const bf16x8*)&KT[row*SP + g4*16 + u*8];
      #pragma unroll
      for (int e=0;e<8;e++) s += (float)k8[e];
    }
    s += __shfl_xor(s,16); s += __shfl_xor(s,32);
    if (g4==0) ksum[(size_t)blk*64 + row] = s;
  }
}

// ---------------- pass2: exclusive prefix scan over chunks ----------------
__global__ __launch_bounds__(256) void pass2_k(const float* __restrict__ SkvT, const float* __restrict__ ksum,
                                               bf16* __restrict__ Sexcl, float* __restrict__ ksx)
{
  int gid = blockIdx.x*256 + threadIdx.x;
  if (gid < BHn*4096){
    int bh = gid >> 12, e = gid & 4095;
    float run = 0.f;
    size_t base = (size_t)bh*NT*4096 + e;
    #pragma unroll 4
    for (int t=0;t<NT;t++){
      Sexcl[base + (size_t)t*4096] = (bf16)run;
      run += SkvT[base + (size_t)t*4096];
    }
  } else if (gid < BHn*4096 + BHn*64){
    int g2 = gid - BHn*4096;
    int bh = g2 >> 6, d = g2 & 63;
    float run = 0.f;
    size_t base = (size_t)bh*NT*64 + d;
    #pragma unroll 4
    for (int t=0;t<NT;t++){
      ksx[base + (size_t)t*64] = run;
      run += ksum[base + (size_t)t*64];
    }
  }
}

// ---------------- pass3: per (b,h,chunk) output, 4-wave blocks ----------------
// O = (mask(Q Kc^T) Vc + Q Sprev) / max(q.ksum_prev + rowsum(mask(Q Kc^T)), 1e-6)
// Wave `w` owns the 16-row i-strip [w*16, w*16+16). V transposed in LDS (one shot).
__global__ __launch_bounds__(256) void pass3_k(const bf16* __restrict__ Q, const bf16* __restrict__ Kn,
                                               const bf16* __restrict__ Sexcl, const bf16* __restrict__ Vn,
                                               const float* __restrict__ ksx, bf16* __restrict__ Obuf)
{
  __shared__ bf16 P[64*SP];
  __shared__ bf16 VT[64*SP];
  const int blk = blockIdx.x;
  const int bh = blk>>5, t = blk&(NT-1);
  const int b = bh>>4, h = bh&15;
  const int tid = threadIdx.x;
  const int w = tid>>6, lane = tid&63;
  const int lrow = lane&15, g4 = lane>>4, lk8 = g4*8;
  const int sj = tid>>2, c4 = tid&3;
  const bf16* qb = Q  + ((size_t)(b*LL + t*CHUNK))*HID + h*HD;
  const bf16* kb = Kn + ((size_t)(b*LL + t*CHUNK))*HID + h*HD;
  const bf16* vb = Vn + ((size_t)(b*LL + t*CHUNK))*HID + h*HD;

  // V load (coalesced) -> LDS transpose, one shot
  {
    const bf16* vs = vb + (size_t)sj*HID + c4*16;
    bf16x8 vr0 = *(const bf16x8*)&vs[0], vr1 = *(const bf16x8*)&vs[8];
    #pragma unroll
    for (int e=0;e<8;e++){
      VT[(c4*16+e)*SP + sj]   = vr0[e];
      VT[(c4*16+8+e)*SP + sj] = vr1[e];
    }
  }

  // Q strip (own rows) + full K tile
  bf16x8 aq[2], bk[4][2];
  #pragma unroll
  for (int kk=0;kk<2;kk++){
    aq[kk] = *(const bf16x8*)&qb[(size_t)(w*16+lrow)*HID + kk*32 + lk8];
    #pragma unroll
    for (int j=0;j<4;j++)
      bk[j][kk] = *(const bf16x8*)&kb[(size_t)(j*16+lrow)*HID + kk*32 + lk8];
  }
  // QK^T strip
  f32x4 sacc[4] = {};
  #pragma unroll
  for (int kk=0;kk<2;kk++)
    #pragma unroll
    for (int j=0;j<4;j++)
      sacc[j] = mfma16(aq[kk], bk[j][kk], sacc[j]);
  // causal mask + row sums
  float rs[4];
  #pragma unroll
  for (int r=0;r<4;r++){
    int irow = w*16 + g4*4 + r;
    float p = 0.f;
    #pragma unroll
    for (int j=0;j<4;j++){
      int jcol = j*16 + lrow;
      float v = (jcol <= irow) ? sacc[j][r] : 0.f;
      sacc[j][r] = v;
      p += v;
    }
    p += __shfl_xor(p,1); p += __shfl_xor(p,2);
    p += __shfl_xor(p,4); p += __shfl_xor(p,8);
    rs[r] = p;
  }
  // P strip -> LDS
  #pragma unroll
  for (int j=0;j<4;j++)
    #pragma unroll
    for (int r=0;r<4;r++)
      P[(w*16+g4*4+r)*SP + j*16+lrow] = (bf16)sacc[j][r];
  // normalizer inter part: z = q_row . ksum_prev
  const float* kp = ksx + (size_t)blk*64;
  float zA;
  {
    float s = 0.f;
    #pragma unroll
    for (int kk=0;kk<2;kk++){
      const float* k8 = kp + kk*32 + lk8;
      bf16x8 q = aq[kk];
      #pragma unroll
      for (int j=0;j<8;j++) s += (float)q[j] * k8[j];
    }
    s += __shfl_xor(s,16); s += __shfl_xor(s,32);
    zA = s;
  }
  // inter: O += Q @ Sprev
  const bf16* sb = Sexcl + (size_t)blk*4096;
  f32x4 oacc[4] = {};
  #pragma unroll
  for (int kk=0;kk<2;kk++)
    #pragma unroll
    for (int j=0;j<4;j++){
      bf16x8 bs = *(const bf16x8*)&sb[(size_t)(j*16+lrow)*64 + kk*32 + lk8];
      oacc[j] = mfma16(aq[kk], bs, oacc[j]);
    }
  __syncthreads();                         // P strips + VT visible
  // intra: O += P @ Vc
  #pragma unroll
  for (int kk=0;kk<2;kk++){
    bf16x8 ap = *(const bf16x8*)&P[(w*16+lrow)*SP + kk*32 + lk8];
    #pragma unroll
    for (int j=0;j<4;j++){
      bf16x8 bv = *(const bf16x8*)&VT[(j*16+lrow)*SP + kk*32 + lk8];
      oacc[j] = mfma16(ap, bv, oacc[j]);
    }
  }
  // normalize + store
  bf16* ob = Obuf + ((size_t)(b*LL + t*CHUNK))*HID + h*HD;
  #pragma unroll
  for (int r=0;r<4;r++){
    float z = __shfl(zA, g4*4 + r) + rs[r];
    z = fmaxf(z, 1e-6f);
    float inv = 1.0f/z;
    int irow = w*16 + g4*4 + r;
    #pragma unroll
    for (int j=0;j<4;j++)
      ob[(size_t)irow*HID + j*16+lrow] = (bf16)(oacc[j][r]*inv);
  }
}

// ---------------- launch ----------------
extern "C" void kernel_launch(void* const* d_in, const int* in_sizes, int n_in,
                              void* d_out, int out_size, void* d_ws, size_t ws_size,
                              hipStream_t stream)
{
  const float* x  = (const float*)d_in[0];
  const float* Wq = (const float*)d_in[1];
  const float* Wk = (const float*)d_in[2];
  const float* Wv = (const float*)d_in[3];
  const float* Wo = (const float*)d_in[4];
  float* out = (float*)d_out;

  char* p = (char*)d_ws;
  auto alloc = [&](size_t bytes){ void* r = (void*)p; p += (bytes + 255) & ~(size_t)255; return r; };
  bf16* xb   = (bf16*)alloc((size_t)MM*HID*2);
  bf16* Wqb  = (bf16*)alloc((size_t)HID*HID*2);
  bf16* Wkb  = (bf16*)alloc((size_t)HID*HID*2);
  bf16* Wvb  = (bf16*)alloc((size_t)HID*HID*2);
  bf16* Wob  = (bf16*)alloc((size_t)HID*HID*2);
  bf16* Qb   = (bf16*)alloc((size_t)MM*HID*2);
  bf16* Knb  = (bf16*)alloc((size_t)MM*HID*2);
  bf16* Vnb  = (bf16*)alloc((size_t)MM*HID*2);
  bf16* Ob   = (bf16*)alloc((size_t)MM*HID*2);
  float* SkvT  = (float*)alloc((size_t)BHn*NT*4096*4);  // 16 MB
  bf16*  Sexcl = (bf16*) alloc((size_t)BHn*NT*4096*2);  // 8 MB
  float* ksum  = (float*)alloc((size_t)BHn*NT*64*4);
  float* ksx   = (float*)alloc((size_t)BHn*NT*64*4);

  cast_all_k<<<dim3(8192), 256, 0, stream>>>(x, Wq,Wk,Wv,Wo, xb, Wqb,Wkb,Wvb,Wob);
  gemm8_k<0><<<dim3(12,16), 512, 0, stream>>>(xb, Wqb,Wkb,Wvb, Qb,Knb,Vnb, nullptr);
  pass1_k<<<dim3(BHn*NT), 256, 0, stream>>>(Knb, Vnb, SkvT, ksum);
  pass2_k<<<dim3((BHn*4096 + BHn*64 + 255)/256), 256, 0, stream>>>(SkvT, ksum, Sexcl, ksx);
  pass3_k<<<dim3(BHn*NT), 256, 0, stream>>>(Qb, Knb, Sexcl, Vnb, ksx, Ob);
  gemm8_k<1><<<dim3(8,32), 512, 0, stream>>>(Ob, Wob,nullptr,nullptr, nullptr,nullptr,nullptr, out);
}

// Round 7
// 156.709 us; speedup vs baseline: 1.1617x; 1.0150x over previous
//
#include <hip/hip_runtime.h>
#include <cstdint>
#include <cstddef>

#define HID 1024
#define NH 16
#define HD 64
#define BB 2
#define LL 2048
#define MM (BB*LL)       // 4096 rows
#define CHUNK 64
#define NT (LL/CHUNK)    // 32 chunks
#define BHn (BB*NH)      // 32 (b,h) chains
#define SP 72            // LDS pad stride (multiple of 8 for b128 reads)

typedef __bf16 bf16;
typedef __attribute__((ext_vector_type(8))) __bf16 bf16x8;
typedef __attribute__((ext_vector_type(4))) float f32x4;

__device__ __forceinline__ f32x4 mfma16(bf16x8 a, bf16x8 b, f32x4 c){
  return __builtin_amdgcn_mfma_f32_16x16x32_bf16(a, b, c, 0, 0, 0);
}

__device__ __forceinline__ void gload16(const void* g, void* l){
  __builtin_amdgcn_global_load_lds(
      (const __attribute__((address_space(1))) unsigned int*)g,
      (__attribute__((address_space(3))) unsigned int*)l, 16, 0, 0);
}

__device__ __forceinline__ void barx(){
  asm volatile("" ::: "memory");
  __builtin_amdgcn_s_barrier();
  asm volatile("" ::: "memory");
}

#define WAITVM(N) asm volatile("s_waitcnt vmcnt(" #N ")" ::: "memory")

// ---------------- fused cast fp32 -> bf16, 8 elems/thread ----------------
__global__ __launch_bounds__(256) void cast_all_k(
    const float* __restrict__ x,  const float* __restrict__ w0,
    const float* __restrict__ w1, const float* __restrict__ w2, const float* __restrict__ w3,
    bf16* __restrict__ xb, bf16* __restrict__ d0, bf16* __restrict__ d1,
    bf16* __restrict__ d2, bf16* __restrict__ d3)
{
  int bid = blockIdx.x;                   // 0..4095
  const float* s; bf16* d; int base;
  if (bid < 2048){ s = x; d = xb; base = bid; }           // 4M elems
  else {
    int w = (bid - 2048) >> 9, r = (bid - 2048) & 511;    // 1M elems each
    s = (w==0)?w0:(w==1)?w1:(w==2)?w2:w3;
    d = (w==0)?d0:(w==1)?d1:(w==2)?d2:d3;
    base = r;
  }
  size_t i = (size_t)(base*256 + threadIdx.x) * 8;
  float4 v0 = *(const float4*)(s + i);
  float4 v1 = *(const float4*)(s + i + 4);
  union { bf16 h[8]; uint4 u; } pk;
  pk.h[0]=(bf16)v0.x; pk.h[1]=(bf16)v0.y; pk.h[2]=(bf16)v0.z; pk.h[3]=(bf16)v0.w;
  pk.h[4]=(bf16)v1.x; pk.h[5]=(bf16)v1.y; pk.h[6]=(bf16)v1.z; pk.h[7]=(bf16)v1.w;
  *(uint4*)(d + i) = pk.u;
}

// ---------------- software-pipelined 8-wave 128x128 GEMM ----------------
// C[m,n] = sum_k A[m,k]*W[n,k].  BK=32, NKT=32 K-tiles.  BM=BN=128 both modes:
// 64 KiB LDS (4 bufs x {A,B} x 128x32) -> 2 blocks/CU, 16 waves/CU.
// MODE 0: QKV fused, grid (24,32): wsel=bn>>3 picks Wq/Wk/Wv, bn&=7; elu+1 on Q,K.
// MODE 1: out-proj, grid (8,32), fp32 store.
// Pipeline per iter t: stage tile t+3; vmcnt(4) [tile t+1 landed]; barrier;
// ds_read frags(t+1) into spare reg set; MFMA(t) on current set. vmcnt->0 only at tail.
// XOR swizzle chunk^((row>>1)&3) on global source + ds_read addr (gload dest linear).
template<int MODE>
__global__ __launch_bounds__(512, 2) void gemm8_k(
    const bf16* __restrict__ A,
    const bf16* __restrict__ W0, const bf16* __restrict__ W1, const bf16* __restrict__ W2,
    bf16* __restrict__ Qo, bf16* __restrict__ Kn, bf16* __restrict__ Vn,
    float* __restrict__ Outf)
{
  constexpr int NKT = HID/32;
  __shared__ bf16 lds[4][2][128*32];

  const int tid = threadIdx.x;
  const int wv = tid >> 6, lane = tid & 63;
  const int lrow = lane & 15, g4 = lane >> 4;
  const int wr = wv >> 2, wc = wv & 3;
  int bn = blockIdx.x, wsel = 0;
  const bf16* W = W0;
  if (MODE==0){ wsel = bn >> 3; bn &= 7; W = (wsel==0)?W0:((wsel==1)?W1:W2); }
  const int row0 = blockIdx.y*128, col0 = bn*128;

  const int sr = tid >> 2, sc = tid & 3;
  const int scs = sc ^ ((sr>>1)&3);              // pre-swizzled source chunk
  const bf16* gA = A + (size_t)(row0 + sr)*HID + scs*8;
  const bf16* gB = W + (size_t)(col0 + sr)*HID + scs*8;
  const int ldst = tid*8;

  auto stage_tile = [&](int u){
    const int buf = u & 3;
    gload16(gA + u*32, (void*)&lds[buf][0][ldst]);
    gload16(gB + u*32, (void*)&lds[buf][1][ldst]);
  };

  const int koff = (g4 ^ ((lrow>>1)&3)) << 3;    // swizzled chunk on read

  auto read_frags = [&](int u, bf16x8 (&fa)[4], bf16x8 (&fb)[2]){
    const int buf = u & 3;
    #pragma unroll
    for (int i=0;i<4;i++)
      fa[i] = *(const bf16x8*)&lds[buf][0][((wr*64 + i*16+lrow)<<5) + koff];
    #pragma unroll
    for (int j=0;j<2;j++)
      fb[j] = *(const bf16x8*)&lds[buf][1][((wc*32 + j*16+lrow)<<5) + koff];
  };

  f32x4 acc[4][2] = {};
  auto do_mfma = [&](bf16x8 (&fa)[4], bf16x8 (&fb)[2]){
    __builtin_amdgcn_s_setprio(1);
    #pragma unroll
    for (int i=0;i<4;i++)
      #pragma unroll
      for (int j=0;j<2;j++)
        acc[i][j] = mfma16(fa[i], fb[j], acc[i][j]);
    __builtin_amdgcn_s_setprio(0);
  };

  stage_tile(0); stage_tile(1); stage_tile(2);
  WAITVM(4);
  barx();
  bf16x8 fEa[4], fEb[2], fOa[4], fOb[2];
  read_frags(0, fEa, fEb);

  for (int t=0; t<NKT; t+=2){
    if (t+3 < NKT)      { stage_tile(t+3); WAITVM(4); }
    else if (t+3 == NKT){ WAITVM(2); }
    else                { WAITVM(0); }
    barx();
    read_frags(t+1, fOa, fOb);
    do_mfma(fEa, fEb);
    const int t2 = t+1;
    if (t2 < NKT-1){
      if (t2+3 < NKT)      { stage_tile(t2+3); WAITVM(4); }
      else if (t2+3 == NKT){ WAITVM(2); }
      else                 { WAITVM(0); }
      barx();
      read_frags(t2+1, fEa, fEb);
    }
    do_mfma(fOa, fOb);
  }

  #pragma unroll
  for (int i=0;i<4;i++){
    const int m0 = row0 + wr*64 + i*16 + g4*4;
    #pragma unroll
    for (int j=0;j<2;j++){
      const int c = col0 + wc*32 + j*16 + lrow;
      #pragma unroll
      for (int r=0;r<4;r++){
        float v = acc[i][j][r];
        if (MODE==1){
          Outf[(size_t)(m0+r)*HID + c] = v;
        } else {
          if (wsel<2) v = v>0.f ? v+1.f : __expf(v);   // elu(v)+1
          bf16 bv = (bf16)v;
          if      (wsel==0) Qo[(size_t)(m0+r)*HID + c] = bv;
          else if (wsel==1) Kn[(size_t)(m0+r)*HID + c] = bv;
          else              Vn[(size_t)(m0+r)*HID + c] = bv;
        }
      }
    }
  }
}

// ---------------- pass1: per-chunk SkvT + ksum, 4-wave blocks, in-LDS transpose --------
__global__ __launch_bounds__(256) void pass1_k(const bf16* __restrict__ Kn, const bf16* __restrict__ Vn,
                                               float* __restrict__ SkvT, float* __restrict__ ksum)
{
  __shared__ bf16 KT[64*SP];
  __shared__ bf16 VT[64*SP];
  const int blk = blockIdx.x;                 // bh*NT + t
  const int bh = blk >> 5, t = blk & (NT-1);
  const int b = bh>>4, h = bh&15;
  const int tid = threadIdx.x;
  const int we = tid >> 6, lane = tid & 63;
  const int lrow = lane&15, g4 = lane>>4, lk8 = g4*8;
  const int sj = tid >> 2, c4 = tid & 3;      // staging: 4 threads per source row
  const bf16* kb = Kn + ((size_t)(b*LL + t*CHUNK))*HID + h*HD;
  const bf16* vb = Vn + ((size_t)(b*LL + t*CHUNK))*HID + h*HD;

  {
    const bf16* ks = kb + (size_t)sj*HID + c4*16;
    const bf16* vs = vb + (size_t)sj*HID + c4*16;
    bf16x8 kr0 = *(const bf16x8*)&ks[0], kr1 = *(const bf16x8*)&ks[8];
    bf16x8 vr0 = *(const bf16x8*)&vs[0], vr1 = *(const bf16x8*)&vs[8];
    #pragma unroll
    for (int e=0;e<8;e++){
      KT[(c4*16+e)*SP + sj]   = kr0[e];
      KT[(c4*16+8+e)*SP + sj] = kr1[e];
      VT[(c4*16+e)*SP + sj]   = vr0[e];
      VT[(c4*16+8+e)*SP + sj] = vr1[e];
    }
  }
  __syncthreads();

  f32x4 acc[4] = {};
  #pragma unroll
  for (int kk=0;kk<2;kk++){
    bf16x8 fa = *(const bf16x8*)&VT[(we*16 + lrow)*SP + kk*32 + lk8];
    #pragma unroll
    for (int j=0;j<4;j++){
      bf16x8 fb = *(const bf16x8*)&KT[(j*16 + lrow)*SP + kk*32 + lk8];
      acc[j] = mfma16(fa, fb, acc[j]);
    }
  }
  float* so = SkvT + (size_t)blk*4096;
  #pragma unroll
  for (int j=0;j<4;j++)
    #pragma unroll
    for (int r=0;r<4;r++)
      so[(we*16 + g4*4 + r)*64 + j*16 + lrow] = acc[j][r];

  {
    const int row = we*16 + lrow;
    float s = 0.f;
    #pragma unroll
    for (int u=0;u<2;u++){
      bf16x8 k8 = *(const bf16x8*)&KT[row*SP + g4*16 + u*8];
      #pragma unroll
      for (int e=0;e<8;e++) s += (float)k8[e];
    }
    s += __shfl_xor(s,16); s += __shfl_xor(s,32);
    if (g4==0) ksum[(size_t)blk*64 + row] = s;
  }
}

// ---------------- pass2: exclusive prefix scan over chunks ----------------
__global__ __launch_bounds__(256) void pass2_k(const float* __restrict__ SkvT, const float* __restrict__ ksum,
                                               bf16* __restrict__ Sexcl, float* __restrict__ ksx)
{
  int gid = blockIdx.x*256 + threadIdx.x;
  if (gid < BHn*4096){
    int bh = gid >> 12, e = gid & 4095;
    float run = 0.f;
    size_t base = (size_t)bh*NT*4096 + e;
    #pragma unroll 4
    for (int t=0;t<NT;t++){
      Sexcl[base + (size_t)t*4096] = (bf16)run;
      run += SkvT[base + (size_t)t*4096];
    }
  } else if (gid < BHn*4096 + BHn*64){
    int g2 = gid - BHn*4096;
    int bh = g2 >> 6, d = g2 & 63;
    float run = 0.f;
    size_t base = (size_t)bh*NT*64 + d;
    #pragma unroll 4
    for (int t=0;t<NT;t++){
      ksx[base + (size_t)t*64] = run;
      run += ksum[base + (size_t)t*64];
    }
  }
}

// ---------------- pass3: per (b,h,chunk) output, 4-wave blocks ----------------
__global__ __launch_bounds__(256) void pass3_k(const bf16* __restrict__ Q, const bf16* __restrict__ Kn,
                                               const bf16* __restrict__ Sexcl, const bf16* __restrict__ Vn,
                                               const float* __restrict__ ksx, bf16* __restrict__ Obuf)
{
  __shared__ bf16 P[64*SP];
  __shared__ bf16 VT[64*SP];
  const int blk = blockIdx.x;
  const int bh = blk>>5, t = blk&(NT-1);
  const int b = bh>>4, h = bh&15;
  const int tid = threadIdx.x;
  const int w = tid>>6, lane = tid&63;
  const int lrow = lane&15, g4 = lane>>4, lk8 = g4*8;
  const int sj = tid>>2, c4 = tid&3;
  const bf16* qb = Q  + ((size_t)(b*LL + t*CHUNK))*HID + h*HD;
  const bf16* kb = Kn + ((size_t)(b*LL + t*CHUNK))*HID + h*HD;
  const bf16* vb = Vn + ((size_t)(b*LL + t*CHUNK))*HID + h*HD;

  {
    const bf16* vs = vb + (size_t)sj*HID + c4*16;
    bf16x8 vr0 = *(const bf16x8*)&vs[0], vr1 = *(const bf16x8*)&vs[8];
    #pragma unroll
    for (int e=0;e<8;e++){
      VT[(c4*16+e)*SP + sj]   = vr0[e];
      VT[(c4*16+8+e)*SP + sj] = vr1[e];
    }
  }

  bf16x8 aq[2], bk[4][2];
  #pragma unroll
  for (int kk=0;kk<2;kk++){
    aq[kk] = *(const bf16x8*)&qb[(size_t)(w*16+lrow)*HID + kk*32 + lk8];
    #pragma unroll
    for (int j=0;j<4;j++)
      bk[j][kk] = *(const bf16x8*)&kb[(size_t)(j*16+lrow)*HID + kk*32 + lk8];
  }
  f32x4 sacc[4] = {};
  #pragma unroll
  for (int kk=0;kk<2;kk++)
    #pragma unroll
    for (int j=0;j<4;j++)
      sacc[j] = mfma16(aq[kk], bk[j][kk], sacc[j]);
  float rs[4];
  #pragma unroll
  for (int r=0;r<4;r++){
    int irow = w*16 + g4*4 + r;
    float p = 0.f;
    #pragma unroll
    for (int j=0;j<4;j++){
      int jcol = j*16 + lrow;
      float v = (jcol <= irow) ? sacc[j][r] : 0.f;
      sacc[j][r] = v;
      p += v;
    }
    p += __shfl_xor(p,1); p += __shfl_xor(p,2);
    p += __shfl_xor(p,4); p += __shfl_xor(p,8);
    rs[r] = p;
  }
  #pragma unroll
  for (int j=0;j<4;j++)
    #pragma unroll
    for (int r=0;r<4;r++)
      P[(w*16+g4*4+r)*SP + j*16+lrow] = (bf16)sacc[j][r];
  const float* kp = ksx + (size_t)blk*64;
  float zA;
  {
    float s = 0.f;
    #pragma unroll
    for (int kk=0;kk<2;kk++){
      const float* k8 = kp + kk*32 + lk8;
      bf16x8 q = aq[kk];
      #pragma unroll
      for (int j=0;j<8;j++) s += (float)q[j] * k8[j];
    }
    s += __shfl_xor(s,16); s += __shfl_xor(s,32);
    zA = s;
  }
  const bf16* sb = Sexcl + (size_t)blk*4096;
  f32x4 oacc[4] = {};
  #pragma unroll
  for (int kk=0;kk<2;kk++)
    #pragma unroll
    for (int j=0;j<4;j++){
      bf16x8 bs = *(const bf16x8*)&sb[(size_t)(j*16+lrow)*64 + kk*32 + lk8];
      oacc[j] = mfma16(aq[kk], bs, oacc[j]);
    }
  __syncthreads();
  #pragma unroll
  for (int kk=0;kk<2;kk++){
    bf16x8 ap = *(const bf16x8*)&P[(w*16+lrow)*SP + kk*32 + lk8];
    #pragma unroll
    for (int j=0;j<4;j++){
      bf16x8 bv = *(const bf16x8*)&VT[(j*16+lrow)*SP + kk*32 + lk8];
      oacc[j] = mfma16(ap, bv, oacc[j]);
    }
  }
  bf16* ob = Obuf + ((size_t)(b*LL + t*CHUNK))*HID + h*HD;
  #pragma unroll
  for (int r=0;r<4;r++){
    float z = __shfl(zA, g4*4 + r) + rs[r];
    z = fmaxf(z, 1e-6f);
    float inv = 1.0f/z;
    int irow = w*16 + g4*4 + r;
    #pragma unroll
    for (int j=0;j<4;j++)
      ob[(size_t)irow*HID + j*16+lrow] = (bf16)(oacc[j][r]*inv);
  }
}

// ---------------- launch ----------------
extern "C" void kernel_launch(void* const* d_in, const int* in_sizes, int n_in,
                              void* d_out, int out_size, void* d_ws, size_t ws_size,
                              hipStream_t stream)
{
  const float* x  = (const float*)d_in[0];
  const float* Wq = (const float*)d_in[1];
  const float* Wk = (const float*)d_in[2];
  const float* Wv = (const float*)d_in[3];
  const float* Wo = (const float*)d_in[4];
  float* out = (float*)d_out;

  char* p = (char*)d_ws;
  auto alloc = [&](size_t bytes){ void* r = (void*)p; p += (bytes + 255) & ~(size_t)255; return r; };
  bf16* xb   = (bf16*)alloc((size_t)MM*HID*2);
  bf16* Wqb  = (bf16*)alloc((size_t)HID*HID*2);
  bf16* Wkb  = (bf16*)alloc((size_t)HID*HID*2);
  bf16* Wvb  = (bf16*)alloc((size_t)HID*HID*2);
  bf16* Wob  = (bf16*)alloc((size_t)HID*HID*2);
  bf16* Qb   = (bf16*)alloc((size_t)MM*HID*2);
  bf16* Knb  = (bf16*)alloc((size_t)MM*HID*2);
  bf16* Vnb  = (bf16*)alloc((size_t)MM*HID*2);
  bf16* Ob   = (bf16*)alloc((size_t)MM*HID*2);
  float* SkvT  = (float*)alloc((size_t)BHn*NT*4096*4);  // 16 MB
  bf16*  Sexcl = (bf16*) alloc((size_t)BHn*NT*4096*2);  // 8 MB
  float* ksum  = (float*)alloc((size_t)BHn*NT*64*4);
  float* ksx   = (float*)alloc((size_t)BHn*NT*64*4);

  cast_all_k<<<dim3(4096), 256, 0, stream>>>(x, Wq,Wk,Wv,Wo, xb, Wqb,Wkb,Wvb,Wob);
  gemm8_k<0><<<dim3(24,32), 512, 0, stream>>>(xb, Wqb,Wkb,Wvb, Qb,Knb,Vnb, nullptr);
  pass1_k<<<dim3(BHn*NT), 256, 0, stream>>>(Knb, Vnb, SkvT, ksum);
  pass2_k<<<dim3((BHn*4096 + BHn*64 + 255)/256), 256, 0, stream>>>(SkvT, ksum, Sexcl, ksx);
  pass3_k<<<dim3(BHn*NT), 256, 0, stream>>>(Qb, Knb, Sexcl, Vnb, ksx, Ob);
  gemm8_k<1><<<dim3(8,32), 512, 0, stream>>>(Ob, Wob,nullptr,nullptr, nullptr,nullptr,nullptr, out);
}

// Round 8
// 150.423 us; speedup vs baseline: 1.2102x; 1.0418x over previous
//
#include <hip/hip_runtime.h>
#include <cstdint>
#include <cstddef>

#define HID 1024
#define NH 16
#define HD 64
#define BB 2
#define LL 2048
#define MM (BB*LL)       // 4096 rows
#define CHUNK 64
#define NT (LL/CHUNK)    // 32 chunks
#define NSEG 16          // segments per (b,h): 128 rows each (2 chunks)
#define BHn (BB*NH)      // 32 (b,h) chains
#define SP 72            // LDS pad stride (multiple of 8 for b128 reads)

typedef __bf16 bf16;
typedef __attribute__((ext_vector_type(8))) __bf16 bf16x8;
typedef __attribute__((ext_vector_type(4))) float f32x4;

__device__ __forceinline__ f32x4 mfma16(bf16x8 a, bf16x8 b, f32x4 c){
  return __builtin_amdgcn_mfma_f32_16x16x32_bf16(a, b, c, 0, 0, 0);
}

__device__ __forceinline__ void gload16(const void* g, void* l){
  __builtin_amdgcn_global_load_lds(
      (const __attribute__((address_space(1))) unsigned int*)g,
      (__attribute__((address_space(3))) unsigned int*)l, 16, 0, 0);
}

__device__ __forceinline__ void barx(){
  asm volatile("" ::: "memory");
  __builtin_amdgcn_s_barrier();
  asm volatile("" ::: "memory");
}

#define WAITVM(N) asm volatile("s_waitcnt vmcnt(" #N ")" ::: "memory")

// ---------------- fused cast fp32 -> bf16, 8 elems/thread ----------------
__global__ __launch_bounds__(256) void cast_all_k(
    const float* __restrict__ x,  const float* __restrict__ w0,
    const float* __restrict__ w1, const float* __restrict__ w2, const float* __restrict__ w3,
    bf16* __restrict__ xb, bf16* __restrict__ d0, bf16* __restrict__ d1,
    bf16* __restrict__ d2, bf16* __restrict__ d3)
{
  int bid = blockIdx.x;                   // 0..4095
  const float* s; bf16* d; int base;
  if (bid < 2048){ s = x; d = xb; base = bid; }           // 4M elems
  else {
    int w = (bid - 2048) >> 9, r = (bid - 2048) & 511;    // 1M elems each
    s = (w==0)?w0:(w==1)?w1:(w==2)?w2:w3;
    d = (w==0)?d0:(w==1)?d1:(w==2)?d2:d3;
    base = r;
  }
  size_t i = (size_t)(base*256 + threadIdx.x) * 8;
  float4 v0 = *(const float4*)(s + i);
  float4 v1 = *(const float4*)(s + i + 4);
  union { bf16 h[8]; uint4 u; } pk;
  pk.h[0]=(bf16)v0.x; pk.h[1]=(bf16)v0.y; pk.h[2]=(bf16)v0.z; pk.h[3]=(bf16)v0.w;
  pk.h[4]=(bf16)v1.x; pk.h[5]=(bf16)v1.y; pk.h[6]=(bf16)v1.z; pk.h[7]=(bf16)v1.w;
  *(uint4*)(d + i) = pk.u;
}

// ---------------- software-pipelined 8-wave 128x128 GEMM (unchanged r7) ----------------
template<int MODE>
__global__ __launch_bounds__(512, 2) void gemm8_k(
    const bf16* __restrict__ A,
    const bf16* __restrict__ W0, const bf16* __restrict__ W1, const bf16* __restrict__ W2,
    bf16* __restrict__ Qo, bf16* __restrict__ Kn, bf16* __restrict__ Vn,
    float* __restrict__ Outf)
{
  constexpr int NKT = HID/32;
  __shared__ bf16 lds[4][2][128*32];

  const int tid = threadIdx.x;
  const int wv = tid >> 6, lane = tid & 63;
  const int lrow = lane & 15, g4 = lane >> 4;
  const int wr = wv >> 2, wc = wv & 3;
  int bn = blockIdx.x, wsel = 0;
  const bf16* W = W0;
  if (MODE==0){ wsel = bn >> 3; bn &= 7; W = (wsel==0)?W0:((wsel==1)?W1:W2); }
  const int row0 = blockIdx.y*128, col0 = bn*128;

  const int sr = tid >> 2, sc = tid & 3;
  const int scs = sc ^ ((sr>>1)&3);              // pre-swizzled source chunk
  const bf16* gA = A + (size_t)(row0 + sr)*HID + scs*8;
  const bf16* gB = W + (size_t)(col0 + sr)*HID + scs*8;
  const int ldst = tid*8;

  auto stage_tile = [&](int u){
    const int buf = u & 3;
    gload16(gA + u*32, (void*)&lds[buf][0][ldst]);
    gload16(gB + u*32, (void*)&lds[buf][1][ldst]);
  };

  const int koff = (g4 ^ ((lrow>>1)&3)) << 3;    // swizzled chunk on read

  auto read_frags = [&](int u, bf16x8 (&fa)[4], bf16x8 (&fb)[2]){
    const int buf = u & 3;
    #pragma unroll
    for (int i=0;i<4;i++)
      fa[i] = *(const bf16x8*)&lds[buf][0][((wr*64 + i*16+lrow)<<5) + koff];
    #pragma unroll
    for (int j=0;j<2;j++)
      fb[j] = *(const bf16x8*)&lds[buf][1][((wc*32 + j*16+lrow)<<5) + koff];
  };

  f32x4 acc[4][2] = {};
  auto do_mfma = [&](bf16x8 (&fa)[4], bf16x8 (&fb)[2]){
    __builtin_amdgcn_s_setprio(1);
    #pragma unroll
    for (int i=0;i<4;i++)
      #pragma unroll
      for (int j=0;j<2;j++)
        acc[i][j] = mfma16(fa[i], fb[j], acc[i][j]);
    __builtin_amdgcn_s_setprio(0);
  };

  stage_tile(0); stage_tile(1); stage_tile(2);
  WAITVM(4);
  barx();
  bf16x8 fEa[4], fEb[2], fOa[4], fOb[2];
  read_frags(0, fEa, fEb);

  for (int t=0; t<NKT; t+=2){
    if (t+3 < NKT)      { stage_tile(t+3); WAITVM(4); }
    else if (t+3 == NKT){ WAITVM(2); }
    else                { WAITVM(0); }
    barx();
    read_frags(t+1, fOa, fOb);
    do_mfma(fEa, fEb);
    const int t2 = t+1;
    if (t2 < NKT-1){
      if (t2+3 < NKT)      { stage_tile(t2+3); WAITVM(4); }
      else if (t2+3 == NKT){ WAITVM(2); }
      else                 { WAITVM(0); }
      barx();
      read_frags(t2+1, fEa, fEb);
    }
    do_mfma(fOa, fOb);
  }

  #pragma unroll
  for (int i=0;i<4;i++){
    const int m0 = row0 + wr*64 + i*16 + g4*4;
    #pragma unroll
    for (int j=0;j<2;j++){
      const int c = col0 + wc*32 + j*16 + lrow;
      #pragma unroll
      for (int r=0;r<4;r++){
        float v = acc[i][j][r];
        if (MODE==1){
          Outf[(size_t)(m0+r)*HID + c] = v;
        } else {
          if (wsel<2) v = v>0.f ? v+1.f : __expf(v);   // elu(v)+1
          bf16 bv = (bf16)v;
          if      (wsel==0) Qo[(size_t)(m0+r)*HID + c] = bv;
          else if (wsel==1) Kn[(size_t)(m0+r)*HID + c] = bv;
          else              Vn[(size_t)(m0+r)*HID + c] = bv;
        }
      }
    }
  }
}

// ---------------- segsum: per-(b,h,seg) sum of k (x) v over 128 rows + ksum ----------------
// grid = BHn*NSEG = 512 blocks x 256 thr. Wave we owns e-strip [we*16, we*16+16).
// Sseg[e][d] (fp32), kseg[d] (fp32).
__global__ __launch_bounds__(256, 2) void segsum_k(const bf16* __restrict__ Kn, const bf16* __restrict__ Vn,
                                                   float* __restrict__ Sseg, float* __restrict__ kseg)
{
  __shared__ bf16 KT[64*SP];
  __shared__ bf16 VT[64*SP];
  const int bx = blockIdx.x;
  const int bh = bx >> 4, seg = bx & (NSEG-1);
  const int b = bh>>4, h = bh&15;
  const int tid = threadIdx.x;
  const int we = tid >> 6, lane = tid & 63;
  const int lrow = lane&15, g4 = lane>>4, lk8 = g4*8;
  const int sj = tid >> 2, c4 = tid & 3;

  f32x4 acc[4] = {};
  float krow = 0.f;

  #pragma unroll
  for (int c=0;c<2;c++){
    const int cg = seg*2 + c;
    const bf16* kb = Kn + ((size_t)(b*LL + cg*CHUNK))*HID + h*HD;
    const bf16* vb = Vn + ((size_t)(b*LL + cg*CHUNK))*HID + h*HD;
    {
      const bf16* ks = kb + (size_t)sj*HID + c4*16;
      const bf16* vs = vb + (size_t)sj*HID + c4*16;
      bf16x8 kr0 = *(const bf16x8*)&ks[0], kr1 = *(const bf16x8*)&ks[8];
      bf16x8 vr0 = *(const bf16x8*)&vs[0], vr1 = *(const bf16x8*)&vs[8];
      #pragma unroll
      for (int e=0;e<8;e++){
        KT[(c4*16+e)*SP + sj]   = kr0[e];
        KT[(c4*16+8+e)*SP + sj] = kr1[e];
        VT[(c4*16+e)*SP + sj]   = vr0[e];
        VT[(c4*16+8+e)*SP + sj] = vr1[e];
      }
    }
    __syncthreads();
    #pragma unroll
    for (int kk=0;kk<2;kk++){
      bf16x8 fa = *(const bf16x8*)&VT[(we*16 + lrow)*SP + kk*32 + lk8];
      #pragma unroll
      for (int j=0;j<4;j++){
        bf16x8 fb = *(const bf16x8*)&KT[(j*16 + lrow)*SP + kk*32 + lk8];
        acc[j] = mfma16(fa, fb, acc[j]);
      }
    }
    {
      const int row = we*16 + lrow;
      float s = 0.f;
      #pragma unroll
      for (int u=0;u<2;u++){
        bf16x8 k8 = *(const bf16x8*)&KT[row*SP + g4*16 + u*8];
        #pragma unroll
        for (int e=0;e<8;e++) s += (float)k8[e];
      }
      s += __shfl_xor(s,16); s += __shfl_xor(s,32);
      krow += s;                                 // only meaningful on g4==0 lanes
    }
    __syncthreads();                             // protect KT/VT overwrite
  }

  float* so = Sseg + (size_t)bx*4096;
  #pragma unroll
  for (int j=0;j<4;j++)
    #pragma unroll
    for (int r=0;r<4;r++)
      so[(we*16 + g4*4 + r)*64 + j*16 + lrow] = acc[j][r];
  if (g4==0) kseg[(size_t)bx*64 + we*16 + lrow] = krow;
}

// ---------------- segscan: exclusive prefix over NSEG segments ----------------
__global__ __launch_bounds__(256) void segscan_k(const float* __restrict__ Sseg, const float* __restrict__ kseg,
                                                 bf16* __restrict__ Sexb, float* __restrict__ ksxb)
{
  int gid = blockIdx.x*256 + threadIdx.x;
  if (gid < BHn*4096){
    int bh = gid >> 12, e = gid & 4095;
    float run = 0.f;
    size_t base = (size_t)bh*NSEG*4096 + e;
    #pragma unroll 4
    for (int s=0;s<NSEG;s++){
      Sexb[base + (size_t)s*4096] = (bf16)run;
      run += Sseg[base + (size_t)s*4096];
    }
  } else if (gid < BHn*4096 + BHn*64){
    int g2 = gid - BHn*4096;
    int bh = g2 >> 6, d = g2 & 63;
    float run = 0.f;
    size_t base = (size_t)bh*NSEG*64 + d;
    #pragma unroll 4
    for (int s=0;s<NSEG;s++){
      ksxb[base + (size_t)s*64] = run;
      run += kseg[base + (size_t)s*64];
    }
  }
}

// ---------------- attn: per-(b,h,seg) output for 2 chunks, state kept on-chip ----------
// grid = BHn*NSEG = 512 blocks x 256 thr (4 waves).
// chunk loop: QK^T(masked) -> rowsum -> inter(Q @ S_state^T from Sm) -> intra(P @ V)
// -> store O; then S_run += V^T K (fp32 regs, e-strip), mirror to Sm (bf16), ksum update.
__global__ __launch_bounds__(256, 2) void attn_k(const bf16* __restrict__ Q, const bf16* __restrict__ Kn,
                                                 const bf16* __restrict__ Vn, const bf16* __restrict__ Sexb,
                                                 const float* __restrict__ ksxb, bf16* __restrict__ Obuf)
{
  __shared__ bf16 KT[64*SP];
  __shared__ bf16 VT[64*SP];
  __shared__ bf16 P [64*SP];
  __shared__ bf16 Sm[64*SP];
  __shared__ float ksum_lds[64];
  const int bx = blockIdx.x;
  const int bh = bx >> 4, seg = bx & (NSEG-1);
  const int b = bh>>4, h = bh&15;
  const int tid = threadIdx.x;
  const int w = tid >> 6, lane = tid & 63;
  const int lrow = lane&15, g4 = lane>>4, lk8 = g4*8;
  const int sj = tid >> 2, c4 = tid & 3;

  // init: segment-prefix state -> Sm (bf16) and ksum_lds (fp32)
  if (tid < 64) ksum_lds[tid] = ksxb[(size_t)bx*64 + tid];
  {
    const bf16* sp = Sexb + (size_t)bx*4096 + tid*16;
    bf16x8 s0 = *(const bf16x8*)&sp[0], s1 = *(const bf16x8*)&sp[8];
    const int e = tid>>2, d0 = (tid&3)*16;
    *(bf16x8*)&Sm[e*SP + d0]     = s0;
    *(bf16x8*)&Sm[e*SP + d0 + 8] = s1;
  }
  __syncthreads();
  // running state fp32, e-strip C-layout: rows w*16+g4*4+r, cols j*16+lrow
  f32x4 Srun[4];
  #pragma unroll
  for (int j=0;j<4;j++)
    #pragma unroll
    for (int r=0;r<4;r++)
      Srun[j][r] = (float)Sm[(w*16+g4*4+r)*SP + j*16+lrow];

  #pragma unroll
  for (int c=0;c<2;c++){
    const int cg = seg*2 + c;
    const bf16* kb = Kn + ((size_t)(b*LL + cg*CHUNK))*HID + h*HD;
    const bf16* vb = Vn + ((size_t)(b*LL + cg*CHUNK))*HID + h*HD;
    const bf16* qb = Q  + ((size_t)(b*LL + cg*CHUNK))*HID + h*HD;
    // stage K,V transposed into KT,VT
    {
      const bf16* ks = kb + (size_t)sj*HID + c4*16;
      const bf16* vs = vb + (size_t)sj*HID + c4*16;
      bf16x8 kr0 = *(const bf16x8*)&ks[0], kr1 = *(const bf16x8*)&ks[8];
      bf16x8 vr0 = *(const bf16x8*)&vs[0], vr1 = *(const bf16x8*)&vs[8];
      #pragma unroll
      for (int e=0;e<8;e++){
        KT[(c4*16+e)*SP + sj]   = kr0[e];
        KT[(c4*16+8+e)*SP + sj] = kr1[e];
        VT[(c4*16+e)*SP + sj]   = vr0[e];
        VT[(c4*16+8+e)*SP + sj] = vr1[e];
      }
    }
    // Q strip (own rows) + K direct frags (row-major)
    bf16x8 aq[2], bk[4][2];
    #pragma unroll
    for (int kk=0;kk<2;kk++){
      aq[kk] = *(const bf16x8*)&qb[(size_t)(w*16+lrow)*HID + kk*32 + lk8];
      #pragma unroll
      for (int j=0;j<4;j++)
        bk[j][kk] = *(const bf16x8*)&kb[(size_t)(j*16+lrow)*HID + kk*32 + lk8];
    }
    __syncthreads();                     // KT/VT ready; Sm/ksum from prev iter ready
    // QK^T strip
    f32x4 sacc[4] = {};
    #pragma unroll
    for (int kk=0;kk<2;kk++)
      #pragma unroll
      for (int j=0;j<4;j++)
        sacc[j] = mfma16(aq[kk], bk[j][kk], sacc[j]);
    // causal mask + row sums
    float rs[4];
    #pragma unroll
    for (int r=0;r<4;r++){
      int irow = w*16 + g4*4 + r;
      float p = 0.f;
      #pragma unroll
      for (int j=0;j<4;j++){
        int jcol = j*16 + lrow;
        float v = (jcol <= irow) ? sacc[j][r] : 0.f;
        sacc[j][r] = v;
        p += v;
      }
      p += __shfl_xor(p,1); p += __shfl_xor(p,2);
      p += __shfl_xor(p,4); p += __shfl_xor(p,8);
      rs[r] = p;
    }
    // zA = q_row . ksum_state
    float zA;
    {
      float s = 0.f;
      #pragma unroll
      for (int kk=0;kk<2;kk++){
        const float* k8 = ksum_lds + kk*32 + lk8;
        bf16x8 q = aq[kk];
        #pragma unroll
        for (int j=0;j<8;j++) s += (float)q[j] * k8[j];
      }
      s += __shfl_xor(s,16); s += __shfl_xor(s,32);
      zA = s;
    }
    // inter: oacc = Q @ S_state^T (B-frags from Sm)
    f32x4 oacc[4] = {};
    #pragma unroll
    for (int kk=0;kk<2;kk++)
      #pragma unroll
      for (int j=0;j<4;j++){
        bf16x8 bs = *(const bf16x8*)&Sm[(j*16+lrow)*SP + kk*32 + lk8];
        oacc[j] = mfma16(aq[kk], bs, oacc[j]);
      }
    // P strip -> LDS
    #pragma unroll
    for (int j=0;j<4;j++)
      #pragma unroll
      for (int r=0;r<4;r++)
        P[(w*16+g4*4+r)*SP + j*16+lrow] = (bf16)sacc[j][r];
    __syncthreads();                     // P ready; all Sm/KT-for-QK reads done
    // intra: oacc += P @ V
    #pragma unroll
    for (int kk=0;kk<2;kk++){
      bf16x8 ap = *(const bf16x8*)&P[(w*16+lrow)*SP + kk*32 + lk8];
      #pragma unroll
      for (int j=0;j<4;j++){
        bf16x8 bv = *(const bf16x8*)&VT[(j*16+lrow)*SP + kk*32 + lk8];
        oacc[j] = mfma16(ap, bv, oacc[j]);
      }
    }
    // normalize + store
    bf16* ob = Obuf + ((size_t)(b*LL + cg*CHUNK))*HID + h*HD;
    #pragma unroll
    for (int r=0;r<4;r++){
      float z = __shfl(zA, g4*4 + r) + rs[r];
      z = fmaxf(z, 1e-6f);
      float inv = 1.0f/z;
      int irow = w*16 + g4*4 + r;
      #pragma unroll
      for (int j=0;j<4;j++)
        ob[(size_t)irow*HID + j*16+lrow] = (bf16)(oacc[j][r]*inv);
    }
    if (c==0){
      // S_run += V^T K (e-strip), then mirror to Sm
      #pragma unroll
      for (int kk=0;kk<2;kk++){
        bf16x8 fa = *(const bf16x8*)&VT[(w*16+lrow)*SP + kk*32 + lk8];
        #pragma unroll
        for (int j=0;j<4;j++){
          bf16x8 fb = *(const bf16x8*)&KT[(j*16+lrow)*SP + kk*32 + lk8];
          Srun[j] = mfma16(fa, fb, Srun[j]);
        }
      }
      // ksum update (rows of KT)
      {
        const int row = w*16 + lrow;
        float s = 0.f;
        #pragma unroll
        for (int u=0;u<2;u++){
          bf16x8 k8 = *(const bf16x8*)&KT[row*SP + g4*16 + u*8];
          #pragma unroll
          for (int e=0;e<8;e++) s += (float)k8[e];
        }
        s += __shfl_xor(s,16); s += __shfl_xor(s,32);
        if (g4==0) ksum_lds[row] += s;
      }
      #pragma unroll
      for (int j=0;j<4;j++)
        #pragma unroll
        for (int r=0;r<4;r++)
          Sm[(w*16+g4*4+r)*SP + j*16+lrow] = (bf16)Srun[j][r];
    }
    __syncthreads();                     // Sm/ksum updates + VT reads done before next stage
  }
}

// ---------------- launch ----------------
extern "C" void kernel_launch(void* const* d_in, const int* in_sizes, int n_in,
                              void* d_out, int out_size, void* d_ws, size_t ws_size,
                              hipStream_t stream)
{
  const float* x  = (const float*)d_in[0];
  const float* Wq = (const float*)d_in[1];
  const float* Wk = (const float*)d_in[2];
  const float* Wv = (const float*)d_in[3];
  const float* Wo = (const float*)d_in[4];
  float* out = (float*)d_out;

  char* p = (char*)d_ws;
  auto alloc = [&](size_t bytes){ void* r = (void*)p; p += (bytes + 255) & ~(size_t)255; return r; };
  bf16* xb   = (bf16*)alloc((size_t)MM*HID*2);
  bf16* Wqb  = (bf16*)alloc((size_t)HID*HID*2);
  bf16* Wkb  = (bf16*)alloc((size_t)HID*HID*2);
  bf16* Wvb  = (bf16*)alloc((size_t)HID*HID*2);
  bf16* Wob  = (bf16*)alloc((size_t)HID*HID*2);
  bf16* Qb   = (bf16*)alloc((size_t)MM*HID*2);
  bf16* Knb  = (bf16*)alloc((size_t)MM*HID*2);
  bf16* Vnb  = (bf16*)alloc((size_t)MM*HID*2);
  bf16* Ob   = (bf16*)alloc((size_t)MM*HID*2);
  float* Sseg = (float*)alloc((size_t)BHn*NSEG*4096*4);  // 8 MB
  bf16*  Sexb = (bf16*) alloc((size_t)BHn*NSEG*4096*2);  // 4 MB
  float* kseg = (float*)alloc((size_t)BHn*NSEG*64*4);
  float* ksxb = (float*)alloc((size_t)BHn*NSEG*64*4);

  cast_all_k<<<dim3(4096), 256, 0, stream>>>(x, Wq,Wk,Wv,Wo, xb, Wqb,Wkb,Wvb,Wob);
  gemm8_k<0><<<dim3(24,32), 512, 0, stream>>>(xb, Wqb,Wkb,Wvb, Qb,Knb,Vnb, nullptr);
  segsum_k<<<dim3(BHn*NSEG), 256, 0, stream>>>(Knb, Vnb, Sseg, kseg);
  segscan_k<<<dim3((BHn*4096 + BHn*64 + 255)/256), 256, 0, stream>>>(Sseg, kseg, Sexb, ksxb);
  attn_k<<<dim3(BHn*NSEG), 256, 0, stream>>>(Qb, Knb, Vnb, Sexb, ksxb, Ob);
  gemm8_k<1><<<dim3(8,32), 512, 0, stream>>>(Ob, Wob,nullptr,nullptr, nullptr,nullptr,nullptr, out);
}